// Round 2
// 1526.816 us; speedup vs baseline: 1.3303x; 1.3303x over previous
//
#include <hip/hip_runtime.h>
#include <stdint.h>

#define B_ 32
#define N_ 2048
#define D_ 128
#define TQ 16
#define NW 8                 // waves per block
#define CPW (N_ / NW)        // 256 cols per wave
#define NT (CPW / 16)        // 16 col-tiles per wave
#define SCALE 0.08838834764831845f
#define MASK_FILL -65504.0f

typedef __attribute__((ext_vector_type(8))) short short8;
typedef __attribute__((ext_vector_type(4))) float f32x4;
typedef __attribute__((ext_vector_type(4))) int i32x4;

// fp32 -> bf16 bits, round-to-nearest-even (finite inputs only)
static __device__ __forceinline__ short f2bf(float f) {
    unsigned u = __builtin_bit_cast(unsigned, f);
    u += 0x7FFFu + ((u >> 16) & 1u);
    return (short)(u >> 16);
}

// One workgroup = 16 query rows x one batch, fully fused:
//   S^T = K Q^T (MFMA, scores stay in VGPRs) -> mask+softmax in-register ->
//   attn float4 store + P(bf16) -> LDS (swizzled) -> O^T = V^T P^T -> ctx.
__global__ __launch_bounds__(512, 4)
void attn_fused_kernel(const float* __restrict__ Q, const float* __restrict__ K,
                       const float* __restrict__ V, const int* __restrict__ mask,
                       float* __restrict__ attn, float* __restrict__ ctx) {
    extern __shared__ char smem[];
    char*  Pb   = smem;                              // [TQ][N_] bf16, XOR-swizzled (64 KB)
    float* redm = (float*)(smem + TQ * N_ * 2);      // [NW][TQ] partial max
    float* reds = redm + NW * TQ;                    // [NW][TQ] partial sum

    // XCD-contiguous remap: each XCD gets 512 consecutive wgs (= 4 batches of K/V in its L2)
    int wg = blockIdx.x;
    wg = (wg & 7) * (4096 / 8) + (wg >> 3);
    const int b    = wg >> 7;
    const int row0 = (wg & 127) * TQ;

    const int tid  = threadIdx.x;
    const int w    = tid >> 6;       // wave 0..7
    const int lane = tid & 63;
    const int l16  = lane & 15;
    const int quad = lane >> 4;

    const size_t qkvbase = (size_t)b * N_ * D_;

    // ---- Q fragments (B-operand of swapped QK^T): B[k][n=l16] = Q[row0+l16][k] ----
    short8 qf[4];
    {
        const float* qp = Q + qkvbase + (size_t)(row0 + l16) * D_ + quad * 8;
        #pragma unroll
        for (int kt = 0; kt < 4; ++kt) {
            f32x4 x = *(const f32x4*)(qp + kt * 32);
            f32x4 y = *(const f32x4*)(qp + kt * 32 + 4);
            #pragma unroll
            for (int j = 0; j < 4; ++j) { qf[kt][j] = f2bf(x[j]); qf[kt][4 + j] = f2bf(y[j]); }
        }
    }

    // ---- Phase 1: S^T tiles in registers, mask+scale+max fused per tile.
    //      acc[t][r] = masked S[qrow=l16][w*256 + t*16 + quad*4 + r] ----
    const int* mrow = mask + ((size_t)b * N_ + row0 + l16) * N_ + w * CPW + quad * 4;
    f32x4 acc[NT];
    float mmax = -INFINITY;
    #pragma unroll
    for (int t = 0; t < NT; ++t) {
        const int c0 = w * CPW + t * 16;
        const float* kp = K + qkvbase + (size_t)(c0 + l16) * D_ + quad * 8;
        i32x4 mv = *(const i32x4*)(mrow + t * 16);
        f32x4 a = {0.f, 0.f, 0.f, 0.f};
        #pragma unroll
        for (int kt = 0; kt < 4; ++kt) {
            f32x4 x = *(const f32x4*)(kp + kt * 32);
            f32x4 y = *(const f32x4*)(kp + kt * 32 + 4);
            short8 kf;
            #pragma unroll
            for (int j = 0; j < 4; ++j) { kf[j] = f2bf(x[j]); kf[4 + j] = f2bf(y[j]); }
            a = __builtin_amdgcn_mfma_f32_16x16x32_bf16(kf, qf[kt], a, 0, 0, 0);
        }
        #pragma unroll
        for (int r = 0; r < 4; ++r) {
            float s = mv[r] ? a[r] * SCALE : MASK_FILL;
            a[r] = s;
            mmax = fmaxf(mmax, s);
        }
        acc[t] = a;
    }

    // ---- Phase 2: softmax. Row is lane-local (qrow = l16). ----
    // combine the 4 quads holding the same qrow, then cross-wave via LDS
    mmax = fmaxf(mmax, __shfl_xor(mmax, 16));
    mmax = fmaxf(mmax, __shfl_xor(mmax, 32));
    if (quad == 0) redm[w * TQ + l16] = mmax;
    __syncthreads();
    float m = redm[l16];
    #pragma unroll
    for (int w2 = 1; w2 < NW; ++w2) m = fmaxf(m, redm[w2 * TQ + l16]);

    float sum = 0.f;
    #pragma unroll
    for (int t = 0; t < NT; ++t) {
        #pragma unroll
        for (int r = 0; r < 4; ++r) {
            float e = __expf(acc[t][r] - m);
            acc[t][r] = e;
            sum += e;
        }
    }
    sum += __shfl_xor(sum, 16);
    sum += __shfl_xor(sum, 32);
    if (quad == 0) reds[w * TQ + l16] = sum;
    __syncthreads();
    float rsum = reds[l16];
    #pragma unroll
    for (int w2 = 1; w2 < NW; ++w2) rsum += reds[w2 * TQ + l16];
    const float inv = 1.f / rsum;

    // ---- attn write (float4) + normalized P -> LDS bf16 (ds_write_b64, swizzled) ----
    float* arow = attn + ((size_t)b * N_ + row0 + l16) * N_ + w * CPW + quad * 4;
    const unsigned pbase = (unsigned)(l16 * (N_ * 2) + (w * CPW + quad * 4) * 2);
    const unsigned swz   = (unsigned)((l16 & 7) << 4);
    #pragma unroll
    for (int t = 0; t < NT; ++t) {
        f32x4 vout;
        #pragma unroll
        for (int r = 0; r < 4; ++r) vout[r] = acc[t][r] * inv;
        *(f32x4*)(arow + t * 16) = vout;
        unsigned lo = (unsigned)(unsigned short)f2bf(vout[0]) | ((unsigned)(unsigned short)f2bf(vout[1]) << 16);
        unsigned hi = (unsigned)(unsigned short)f2bf(vout[2]) | ((unsigned)(unsigned short)f2bf(vout[3]) << 16);
        *(unsigned long long*)(Pb + ((pbase + t * 32) ^ swz)) = ((unsigned long long)hi << 32) | lo;
    }
    __syncthreads();

    // ---- Phase 3: O^T = V^T P^T. Wave w owns d-cols [w*16, w*16+16). ----
    const int n0 = w * 16;
    f32x4 o = {0.f, 0.f, 0.f, 0.f};
    const unsigned prbase = (unsigned)(l16 * (N_ * 2) + quad * 16);
    const float* vcol = V + qkvbase + (size_t)(quad * 8) * D_ + n0 + l16;
    #pragma unroll 4
    for (int kk = 0; kk < N_; kk += 32) {
        // B-operand: P[qrow=l16][kk+quad*8 .. +8] from swizzled LDS (ds_read_b128, <=2-way bank alias)
        short8 pf = *(const short8*)(Pb + ((prbase + kk * 2) ^ swz));
        // A-operand: V[kk+quad*8+j][n0+l16]
        short8 vf;
        #pragma unroll
        for (int j = 0; j < 8; ++j) vf[j] = f2bf(vcol[(size_t)(kk + j) * D_]);
        o = __builtin_amdgcn_mfma_f32_16x16x32_bf16(vf, pf, o, 0, 0, 0);
    }
    // D: col=l16 -> qrow, row=quad*4+r -> dcol n0+quad*4+r  => float4 ctx store
    float* crow = ctx + ((size_t)b * N_ + row0 + l16) * D_ + n0 + quad * 4;
    *(f32x4*)crow = o;
}

extern "C" void kernel_launch(void* const* d_in, const int* in_sizes, int n_in,
                              void* d_out, int out_size, void* d_ws, size_t ws_size,
                              hipStream_t stream) {
    const float* Q    = (const float*)d_in[0];
    const float* K    = (const float*)d_in[1];
    const float* V    = (const float*)d_in[2];
    const int*   mask = (const int*)d_in[3];

    float* out  = (float*)d_out;
    float* ctx  = out;                         // [B, N, D]
    float* attn = out + (size_t)B_ * N_ * D_;  // [B, N, N]

    dim3 grid(B_ * (N_ / TQ), 1, 1);           // 4096
    dim3 block(512, 1, 1);
    const size_t lds = (size_t)TQ * N_ * 2 + 2 * NW * TQ * sizeof(float);  // 66560 B

    attn_fused_kernel<<<grid, block, lds, stream>>>(Q, K, V, mask, attn, ctx);
}

// Round 3
// 1415.325 us; speedup vs baseline: 1.4350x; 1.0788x over previous
//
#include <hip/hip_runtime.h>
#include <stdint.h>

#define B_ 32
#define N_ 2048
#define D_ 128
#define TQ 16
#define NW 8                 // waves per block
#define CPW (N_ / NW)        // 256 cols per wave
#define NT (CPW / 16)        // 16 col-tiles per wave
#define SCALE 0.08838834764831845f
#define MASK_FILL -65504.0f

typedef __attribute__((ext_vector_type(8))) short short8;
typedef __attribute__((ext_vector_type(4))) float f32x4;
typedef __attribute__((ext_vector_type(4))) int i32x4;
typedef __attribute__((ext_vector_type(4))) unsigned short ushort4_t;
typedef unsigned short ushort_t;

// fp32 -> bf16 bits, round-to-nearest-even (finite inputs only)
static __device__ __forceinline__ short f2bf(float f) {
    unsigned u = __builtin_bit_cast(unsigned, f);
    u += 0x7FFFu + ((u >> 16) & 1u);
    return (short)(u >> 16);
}

// ---- Pre-pass A: X fp32 -> bf16, same layout (for K). 8 el/thread. ----
__global__ __launch_bounds__(256)
void conv_bf16_kernel(const float* __restrict__ X, ushort_t* __restrict__ Y) {
    const size_t i = ((size_t)blockIdx.x * 256 + threadIdx.x) * 8;
    f32x4 a = *(const f32x4*)(X + i);
    f32x4 c = *(const f32x4*)(X + i + 4);
    short8 o;
    #pragma unroll
    for (int j = 0; j < 4; ++j) { o[j] = f2bf(a[j]); o[4 + j] = f2bf(c[j]); }
    *(short8*)(Y + i) = o;
}

// ---- Pre-pass B: V[b][n][d] fp32 -> Vt[b][d][n] bf16, 32x32 LDS tiles. ----
__global__ __launch_bounds__(256)
void conv_vt_kernel(const float* __restrict__ V, ushort_t* __restrict__ Vt) {
    __shared__ ushort_t t[32][34];
    const int tid = threadIdx.x;
    const int b = blockIdx.z, n0 = blockIdx.x * 32, d0 = blockIdx.y * 32;
    {
        const int r = tid >> 3, cg = (tid & 7) * 4;
        f32x4 v = *(const f32x4*)(V + ((size_t)b * N_ + n0 + r) * D_ + d0 + cg);
        #pragma unroll
        for (int j = 0; j < 4; ++j) t[r][cg + j] = (ushort_t)f2bf(v[j]);
    }
    __syncthreads();
    {
        const int d = tid >> 3, ng = (tid & 7) * 4;
        ushort4_t o = { t[ng][d], t[ng + 1][d], t[ng + 2][d], t[ng + 3][d] };
        *(ushort4_t*)(Vt + ((size_t)b * D_ + d0 + d) * N_ + n0 + ng) = o;
    }
}

// One workgroup = 16 query rows x one batch, fully fused.
// PRE=1: K/V pre-converted to bf16 (Kb same layout, Vt transposed) in workspace.
template <int PRE>
__global__ __launch_bounds__(512, 4)
void attn_fused_kernel(const float* __restrict__ Q, const float* __restrict__ K,
                       const ushort_t* __restrict__ Kb, const float* __restrict__ V,
                       const ushort_t* __restrict__ Vt, const int* __restrict__ mask,
                       float* __restrict__ attn, float* __restrict__ ctx) {
    extern __shared__ char smem[];
    char*  Pb   = smem;                              // [TQ][N_] bf16, XOR-swizzled (64 KB)
    float* redm = (float*)(smem + TQ * N_ * 2);      // [NW][TQ] partial max
    float* reds = redm + NW * TQ;                    // [NW][TQ] partial sum

    // XCD-contiguous remap: each XCD gets 512 consecutive wgs (= 4 batches of K/V in its L2)
    int wg = blockIdx.x;
    wg = (wg & 7) * (4096 / 8) + (wg >> 3);
    const int b    = wg >> 7;
    const int row0 = (wg & 127) * TQ;

    const int tid  = threadIdx.x;
    const int w    = tid >> 6;       // wave 0..7
    const int lane = tid & 63;
    const int l16  = lane & 15;
    const int quad = lane >> 4;

    const size_t qkvbase = (size_t)b * N_ * D_;

    // ---- Q fragments (B-operand of swapped QK^T): B[k][n=l16] = Q[row0+l16][k] ----
    short8 qf[4];
    {
        const float* qp = Q + qkvbase + (size_t)(row0 + l16) * D_ + quad * 8;
        #pragma unroll
        for (int kt = 0; kt < 4; ++kt) {
            f32x4 x = *(const f32x4*)(qp + kt * 32);
            f32x4 y = *(const f32x4*)(qp + kt * 32 + 4);
            #pragma unroll
            for (int j = 0; j < 4; ++j) { qf[kt][j] = f2bf(x[j]); qf[kt][4 + j] = f2bf(y[j]); }
        }
    }

    // ---- Phase 1: S^T tiles in registers, mask+scale+max fused per tile.
    //      acc[t][r] = masked S[qrow=l16][w*256 + t*16 + quad*4 + r] ----
    const int* mrow = mask + ((size_t)b * N_ + row0 + l16) * N_ + w * CPW + quad * 4;
    f32x4 acc[NT];
    float mmax = -INFINITY;
    #pragma unroll
    for (int t = 0; t < NT; ++t) {
        const int c0 = w * CPW + t * 16;
        i32x4 mv = __builtin_nontemporal_load((const i32x4*)(mrow + t * 16));
        f32x4 a = {0.f, 0.f, 0.f, 0.f};
        if constexpr (PRE) {
            const ushort_t* kp = Kb + qkvbase + (size_t)(c0 + l16) * D_ + quad * 8;
            #pragma unroll
            for (int kt = 0; kt < 4; ++kt) {
                short8 kf = *(const short8*)(kp + kt * 32);
                a = __builtin_amdgcn_mfma_f32_16x16x32_bf16(kf, qf[kt], a, 0, 0, 0);
            }
        } else {
            const float* kp = K + qkvbase + (size_t)(c0 + l16) * D_ + quad * 8;
            #pragma unroll
            for (int kt = 0; kt < 4; ++kt) {
                f32x4 x = *(const f32x4*)(kp + kt * 32);
                f32x4 y = *(const f32x4*)(kp + kt * 32 + 4);
                short8 kf;
                #pragma unroll
                for (int j = 0; j < 4; ++j) { kf[j] = f2bf(x[j]); kf[4 + j] = f2bf(y[j]); }
                a = __builtin_amdgcn_mfma_f32_16x16x32_bf16(kf, qf[kt], a, 0, 0, 0);
            }
        }
        #pragma unroll
        for (int r = 0; r < 4; ++r) {
            float s = mv[r] ? a[r] * SCALE : MASK_FILL;
            a[r] = s;
            mmax = fmaxf(mmax, s);
        }
        acc[t] = a;
    }

    // ---- Phase 2: softmax. Row is lane-local (qrow = l16). ----
    mmax = fmaxf(mmax, __shfl_xor(mmax, 16));
    mmax = fmaxf(mmax, __shfl_xor(mmax, 32));
    if (quad == 0) redm[w * TQ + l16] = mmax;
    __syncthreads();
    float m = redm[l16];
    #pragma unroll
    for (int w2 = 1; w2 < NW; ++w2) m = fmaxf(m, redm[w2 * TQ + l16]);

    float sum = 0.f;
    #pragma unroll
    for (int t = 0; t < NT; ++t) {
        #pragma unroll
        for (int r = 0; r < 4; ++r) {
            float e = __expf(acc[t][r] - m);
            acc[t][r] = e;
            sum += e;
        }
    }
    sum += __shfl_xor(sum, 16);
    sum += __shfl_xor(sum, 32);
    if (quad == 0) reds[w * TQ + l16] = sum;
    __syncthreads();
    float rsum = reds[l16];
    #pragma unroll
    for (int w2 = 1; w2 < NW; ++w2) rsum += reds[w2 * TQ + l16];
    const float inv = 1.f / rsum;

    // ---- attn write (nontemporal float4) + normalized P -> LDS bf16 (swizzled) ----
    float* arow = attn + ((size_t)b * N_ + row0 + l16) * N_ + w * CPW + quad * 4;
    const unsigned pbase = (unsigned)(l16 * (N_ * 2) + (w * CPW + quad * 4) * 2);
    const unsigned swz   = (unsigned)((l16 & 7) << 4);
    #pragma unroll
    for (int t = 0; t < NT; ++t) {
        f32x4 vout;
        #pragma unroll
        for (int r = 0; r < 4; ++r) vout[r] = acc[t][r] * inv;
        __builtin_nontemporal_store(vout, (f32x4*)(arow + t * 16));
        unsigned lo = (unsigned)(unsigned short)f2bf(vout[0]) | ((unsigned)(unsigned short)f2bf(vout[1]) << 16);
        unsigned hi = (unsigned)(unsigned short)f2bf(vout[2]) | ((unsigned)(unsigned short)f2bf(vout[3]) << 16);
        *(unsigned long long*)(Pb + ((pbase + t * 32) ^ swz)) = ((unsigned long long)hi << 32) | lo;
    }
    __syncthreads();

    // ---- Phase 3: O^T = V^T P^T. Wave w owns d-cols [w*16, w*16+16). ----
    const int n0 = w * 16;
    f32x4 o0 = {0.f, 0.f, 0.f, 0.f};
    f32x4 o1 = {0.f, 0.f, 0.f, 0.f};
    const unsigned prbase = (unsigned)(l16 * (N_ * 2) + quad * 16);
    if constexpr (PRE) {
        const ushort_t* vrow = Vt + qkvbase + (size_t)(n0 + l16) * N_ + quad * 8;
        #pragma unroll 2
        for (int kk = 0; kk < N_; kk += 64) {
            short8 pf0 = *(const short8*)(Pb + ((prbase + kk * 2) ^ swz));
            short8 pf1 = *(const short8*)(Pb + ((prbase + kk * 2 + 64) ^ swz));
            short8 vf0 = *(const short8*)(vrow + kk);
            short8 vf1 = *(const short8*)(vrow + kk + 32);
            o0 = __builtin_amdgcn_mfma_f32_16x16x32_bf16(vf0, pf0, o0, 0, 0, 0);
            o1 = __builtin_amdgcn_mfma_f32_16x16x32_bf16(vf1, pf1, o1, 0, 0, 0);
        }
    } else {
        const float* vcol = V + qkvbase + (size_t)(quad * 8) * D_ + n0 + l16;
        #pragma unroll 2
        for (int kk = 0; kk < N_; kk += 64) {
            short8 pf0 = *(const short8*)(Pb + ((prbase + kk * 2) ^ swz));
            short8 pf1 = *(const short8*)(Pb + ((prbase + kk * 2 + 64) ^ swz));
            short8 vf0, vf1;
            #pragma unroll
            for (int j = 0; j < 8; ++j) {
                vf0[j] = f2bf(vcol[(size_t)(kk + j) * D_]);
                vf1[j] = f2bf(vcol[(size_t)(kk + 32 + j) * D_]);
            }
            o0 = __builtin_amdgcn_mfma_f32_16x16x32_bf16(vf0, pf0, o0, 0, 0, 0);
            o1 = __builtin_amdgcn_mfma_f32_16x16x32_bf16(vf1, pf1, o1, 0, 0, 0);
        }
    }
    f32x4 o = o0 + o1;
    // D: col=l16 -> qrow, row=quad*4+r -> dcol n0+quad*4+r  => float4 ctx store
    float* crow = ctx + ((size_t)b * N_ + row0 + l16) * D_ + n0 + quad * 4;
    __builtin_nontemporal_store(o, (f32x4*)crow);
}

extern "C" void kernel_launch(void* const* d_in, const int* in_sizes, int n_in,
                              void* d_out, int out_size, void* d_ws, size_t ws_size,
                              hipStream_t stream) {
    const float* Q    = (const float*)d_in[0];
    const float* K    = (const float*)d_in[1];
    const float* V    = (const float*)d_in[2];
    const int*   mask = (const int*)d_in[3];

    float* out  = (float*)d_out;
    float* ctx  = out;                         // [B, N, D]
    float* attn = out + (size_t)B_ * N_ * D_;  // [B, N, N]

    dim3 grid(B_ * (N_ / TQ), 1, 1);           // 4096
    dim3 block(512, 1, 1);
    const size_t lds = (size_t)TQ * N_ * 2 + 2 * NW * TQ * sizeof(float);  // 66560 B

    const size_t nel = (size_t)B_ * N_ * D_;   // 8.39M elements
    const size_t ws_need = nel * 2 * 2;        // Kb + Vt bf16 = 32 MB

    if (ws_size >= ws_need) {
        ushort_t* Kb = (ushort_t*)d_ws;
        ushort_t* Vt = Kb + nel;
        conv_bf16_kernel<<<dim3((unsigned)(nel / 8 / 256)), dim3(256), 0, stream>>>(K, Kb);
        conv_vt_kernel<<<dim3(N_ / 32, D_ / 32, B_), dim3(256), 0, stream>>>(V, Vt);
        attn_fused_kernel<1><<<grid, block, lds, stream>>>(Q, K, Kb, V, Vt, mask, attn, ctx);
    } else {
        attn_fused_kernel<0><<<grid, block, lds, stream>>>(Q, K, (const ushort_t*)nullptr,
                                                           V, (const ushort_t*)nullptr,
                                                           mask, attn, ctx);
    }
}

// Round 6
// 1405.852 us; speedup vs baseline: 1.4447x; 1.0067x over previous
//
#include <hip/hip_runtime.h>
#include <stdint.h>

#define B_ 32
#define N_ 2048
#define D_ 128
#define TQ 16
#define NW 8                 // waves per block
#define CPW (N_ / NW)        // 256 cols per wave
#define NT (CPW / 16)        // 16 col-tiles per wave
#define SCALE 0.08838834764831845f
#define MASK_FILL -65504.0f

typedef __attribute__((ext_vector_type(8))) short short8;
typedef __attribute__((ext_vector_type(4))) float f32x4;
typedef __attribute__((ext_vector_type(4))) int i32x4;
typedef __attribute__((ext_vector_type(4))) unsigned short ushort4_t;
typedef unsigned short ushort_t;

// fp32 -> bf16 bits, round-to-nearest-even (finite inputs only)
static __device__ __forceinline__ short f2bf(float f) {
    unsigned u = __builtin_bit_cast(unsigned, f);
    u += 0x7FFFu + ((u >> 16) & 1u);
    return (short)(u >> 16);
}

// ---- Pre-pass A: X fp32 -> bf16, same layout (for K). 8 el/thread. ----
__global__ __launch_bounds__(256)
void conv_bf16_kernel(const float* __restrict__ X, ushort_t* __restrict__ Y) {
    const size_t i = ((size_t)blockIdx.x * 256 + threadIdx.x) * 8;
    f32x4 a = *(const f32x4*)(X + i);
    f32x4 c = *(const f32x4*)(X + i + 4);
    short8 o;
    #pragma unroll
    for (int j = 0; j < 4; ++j) { o[j] = f2bf(a[j]); o[4 + j] = f2bf(c[j]); }
    *(short8*)(Y + i) = o;
}

// ---- Pre-pass B: V[b][n][d] fp32 -> Vt[b][d][n] bf16, 32x32 LDS tiles. ----
__global__ __launch_bounds__(256)
void conv_vt_kernel(const float* __restrict__ V, ushort_t* __restrict__ Vt) {
    __shared__ ushort_t t[32][34];
    const int tid = threadIdx.x;
    const int b = blockIdx.z, n0 = blockIdx.x * 32, d0 = blockIdx.y * 32;
    {
        const int r = tid >> 3, cg = (tid & 7) * 4;
        f32x4 v = *(const f32x4*)(V + ((size_t)b * N_ + n0 + r) * D_ + d0 + cg);
        #pragma unroll
        for (int j = 0; j < 4; ++j) t[r][cg + j] = (ushort_t)f2bf(v[j]);
    }
    __syncthreads();
    {
        const int d = tid >> 3, ng = (tid & 7) * 4;
        ushort4_t o = { t[ng][d], t[ng + 1][d], t[ng + 2][d], t[ng + 3][d] };
        *(ushort4_t*)(Vt + ((size_t)b * D_ + d0 + d) * N_ + n0 + ng) = o;
    }
}

// One workgroup = 16 query rows x one batch, fully fused, software-pipelined.
// PRE=1: K/V pre-converted to bf16 (Kb same layout, Vt transposed) in workspace.
template <int PRE>
__global__ __launch_bounds__(512, 4)
void attn_fused_kernel(const float* __restrict__ Q, const float* __restrict__ K,
                       const ushort_t* __restrict__ Kb, const float* __restrict__ V,
                       const ushort_t* __restrict__ Vt, const int* __restrict__ mask,
                       float* __restrict__ attn, float* __restrict__ ctx) {
    extern __shared__ char smem[];
    char*  Pb   = smem;                              // [TQ][N_] bf16, XOR-swizzled (64 KB)
    float* redm = (float*)(smem + TQ * N_ * 2);      // [NW][TQ] partial max
    float* reds = redm + NW * TQ;                    // [NW][TQ] partial sum

    // XCD-contiguous remap: each XCD gets 512 consecutive wgs (= 4 batches of K/V in its L2)
    int wg = blockIdx.x;
    wg = (wg & 7) * (4096 / 8) + (wg >> 3);
    const int b    = wg >> 7;
    const int row0 = (wg & 127) * TQ;

    const int tid  = threadIdx.x;
    const int w    = tid >> 6;       // wave 0..7
    const int lane = tid & 63;
    const int l16  = lane & 15;
    const int quad = lane >> 4;

    const size_t qkvbase = (size_t)b * N_ * D_;

    // ---- Q fragments (B-operand of swapped QK^T): B[k][n=l16] = Q[row0+l16][k] ----
    short8 qf[4];
    {
        const float* qp = Q + qkvbase + (size_t)(row0 + l16) * D_ + quad * 8;
        #pragma unroll
        for (int kt = 0; kt < 4; ++kt) {
            f32x4 x = *(const f32x4*)(qp + kt * 32);
            f32x4 y = *(const f32x4*)(qp + kt * 32 + 4);
            #pragma unroll
            for (int j = 0; j < 4; ++j) { qf[kt][j] = f2bf(x[j]); qf[kt][4 + j] = f2bf(y[j]); }
        }
    }

    // ---- Phase 1: S^T tiles in registers, pipelined (K depth-2, mask depth-4).
    //      acc[t][r] = masked S[qrow=l16][w*256 + t*16 + quad*4 + r] ----
    const int* mrow = mask + ((size_t)b * N_ + row0 + l16) * N_ + w * CPW + quad * 4;
    f32x4 acc[NT];
    float mmax = -INFINITY;

    if constexpr (PRE) {
        const ushort_t* kbase = Kb + qkvbase + (size_t)(w * CPW + l16) * D_ + quad * 8;
        short8 kfb[2][4];       // K-fragment double buffer (tiles t, t+1)
        i32x4  mvb[4];          // mask rolling buffer (tiles t .. t+3)
        #pragma unroll
        for (int p = 0; p < 2; ++p) {
            const ushort_t* kp = kbase + (size_t)(p * 16) * D_;
            #pragma unroll
            for (int kt = 0; kt < 4; ++kt) kfb[p][kt] = *(const short8*)(kp + kt * 32);
        }
        #pragma unroll
        for (int p = 0; p < 4; ++p) mvb[p] = *(const i32x4*)(mrow + p * 16);

        #pragma unroll
        for (int t = 0; t < NT; ++t) {
            short8 kf0 = kfb[t & 1][0], kf1 = kfb[t & 1][1];
            short8 kf2 = kfb[t & 1][2], kf3 = kfb[t & 1][3];
            i32x4  mv  = mvb[t & 3];
            if (t + 2 < NT) {
                const ushort_t* kp = kbase + (size_t)((t + 2) * 16) * D_;
                #pragma unroll
                for (int kt = 0; kt < 4; ++kt) kfb[t & 1][kt] = *(const short8*)(kp + kt * 32);
            }
            if (t + 4 < NT) mvb[t & 3] = *(const i32x4*)(mrow + (t + 4) * 16);

            f32x4 a = {0.f, 0.f, 0.f, 0.f};
            a = __builtin_amdgcn_mfma_f32_16x16x32_bf16(kf0, qf[0], a, 0, 0, 0);
            a = __builtin_amdgcn_mfma_f32_16x16x32_bf16(kf1, qf[1], a, 0, 0, 0);
            a = __builtin_amdgcn_mfma_f32_16x16x32_bf16(kf2, qf[2], a, 0, 0, 0);
            a = __builtin_amdgcn_mfma_f32_16x16x32_bf16(kf3, qf[3], a, 0, 0, 0);
            #pragma unroll
            for (int r = 0; r < 4; ++r) {
                float s = mv[r] ? a[r] * SCALE : MASK_FILL;
                a[r] = s;
                mmax = fmaxf(mmax, s);
            }
            acc[t] = a;
        }
    } else {
        #pragma unroll
        for (int t = 0; t < NT; ++t) {
            const int c0 = w * CPW + t * 16;
            i32x4 mv = *(const i32x4*)(mrow + t * 16);
            const float* kp = K + qkvbase + (size_t)(c0 + l16) * D_ + quad * 8;
            f32x4 a = {0.f, 0.f, 0.f, 0.f};
            #pragma unroll
            for (int kt = 0; kt < 4; ++kt) {
                f32x4 x = *(const f32x4*)(kp + kt * 32);
                f32x4 y = *(const f32x4*)(kp + kt * 32 + 4);
                short8 kf;
                #pragma unroll
                for (int j = 0; j < 4; ++j) { kf[j] = f2bf(x[j]); kf[4 + j] = f2bf(y[j]); }
                a = __builtin_amdgcn_mfma_f32_16x16x32_bf16(kf, qf[kt], a, 0, 0, 0);
            }
            #pragma unroll
            for (int r = 0; r < 4; ++r) {
                float s = mv[r] ? a[r] * SCALE : MASK_FILL;
                a[r] = s;
                mmax = fmaxf(mmax, s);
            }
            acc[t] = a;
        }
    }

    // ---- Phase 2: softmax. Row is lane-local (qrow = l16). ----
    mmax = fmaxf(mmax, __shfl_xor(mmax, 16));
    mmax = fmaxf(mmax, __shfl_xor(mmax, 32));
    if (quad == 0) redm[w * TQ + l16] = mmax;
    __syncthreads();
    float m = redm[l16];
    #pragma unroll
    for (int w2 = 1; w2 < NW; ++w2) m = fmaxf(m, redm[w2 * TQ + l16]);

    float sum = 0.f;
    #pragma unroll
    for (int t = 0; t < NT; ++t) {
        #pragma unroll
        for (int r = 0; r < 4; ++r) {
            float e = __expf(acc[t][r] - m);
            acc[t][r] = e;
            sum += e;
        }
    }
    sum += __shfl_xor(sum, 16);
    sum += __shfl_xor(sum, 32);
    if (quad == 0) reds[w * TQ + l16] = sum;
    __syncthreads();
    float rsum = reds[l16];
    #pragma unroll
    for (int w2 = 1; w2 < NW; ++w2) rsum += reds[w2 * TQ + l16];
    const float inv = 1.f / rsum;

    // ---- attn write (float4) + normalized P -> LDS bf16 (swizzled) ----
    float* arow = attn + ((size_t)b * N_ + row0 + l16) * N_ + w * CPW + quad * 4;
    const unsigned pbase = (unsigned)(l16 * (N_ * 2) + (w * CPW + quad * 4) * 2);
    const unsigned swz   = (unsigned)((l16 & 7) << 4);
    #pragma unroll
    for (int t = 0; t < NT; ++t) {
        f32x4 vout;
        #pragma unroll
        for (int r = 0; r < 4; ++r) vout[r] = acc[t][r] * inv;
        *(f32x4*)(arow + t * 16) = vout;
        unsigned lo = (unsigned)(unsigned short)f2bf(vout[0]) | ((unsigned)(unsigned short)f2bf(vout[1]) << 16);
        unsigned hi = (unsigned)(unsigned short)f2bf(vout[2]) | ((unsigned)(unsigned short)f2bf(vout[3]) << 16);
        *(unsigned long long*)(Pb + ((pbase + t * 32) ^ swz)) = ((unsigned long long)hi << 32) | lo;
    }
    __syncthreads();

    // ---- Phase 3: O^T = V^T P^T, pipelined (Vt depth-2, LDS depth-1, 4 acc chains).
    //      Wave w owns d-cols [w*16, w*16+16). ----
    const int n0 = w * 16;
    f32x4 o0 = {0.f, 0.f, 0.f, 0.f}, o1 = {0.f, 0.f, 0.f, 0.f};
    f32x4 o2 = {0.f, 0.f, 0.f, 0.f}, o3 = {0.f, 0.f, 0.f, 0.f};
    const unsigned prbase = (unsigned)(l16 * (N_ * 2) + quad * 16);
    if constexpr (PRE) {
        const ushort_t* vrow = Vt + qkvbase + (size_t)(n0 + l16) * N_ + quad * 8;
        short8 vfb[2][2];
        short8 pfc0, pfc1;
        #pragma unroll
        for (int p = 0; p < 2; ++p) {
            vfb[p][0] = *(const short8*)(vrow + p * 64);
            vfb[p][1] = *(const short8*)(vrow + p * 64 + 32);
        }
        pfc0 = *(const short8*)(Pb + ((prbase + 0) ^ swz));
        pfc1 = *(const short8*)(Pb + ((prbase + 64) ^ swz));
        #pragma unroll
        for (int i = 0; i < 32; ++i) {
            short8 v0 = vfb[i & 1][0], v1 = vfb[i & 1][1];
            short8 p0 = pfc0, p1 = pfc1;
            if (i + 2 < 32) {
                vfb[i & 1][0] = *(const short8*)(vrow + (i + 2) * 64);
                vfb[i & 1][1] = *(const short8*)(vrow + (i + 2) * 64 + 32);
            }
            if (i + 1 < 32) {
                pfc0 = *(const short8*)(Pb + ((prbase + (i + 1) * 128) ^ swz));
                pfc1 = *(const short8*)(Pb + ((prbase + (i + 1) * 128 + 64) ^ swz));
            }
            if (i & 1) {
                o2 = __builtin_amdgcn_mfma_f32_16x16x32_bf16(v0, p0, o2, 0, 0, 0);
                o3 = __builtin_amdgcn_mfma_f32_16x16x32_bf16(v1, p1, o3, 0, 0, 0);
            } else {
                o0 = __builtin_amdgcn_mfma_f32_16x16x32_bf16(v0, p0, o0, 0, 0, 0);
                o1 = __builtin_amdgcn_mfma_f32_16x16x32_bf16(v1, p1, o1, 0, 0, 0);
            }
        }
    } else {
        const float* vcol = V + qkvbase + (size_t)(quad * 8) * D_ + n0 + l16;
        #pragma unroll 2
        for (int kk = 0; kk < N_; kk += 64) {
            short8 pf0 = *(const short8*)(Pb + ((prbase + kk * 2) ^ swz));
            short8 pf1 = *(const short8*)(Pb + ((prbase + kk * 2 + 64) ^ swz));
            short8 vf0, vf1;
            #pragma unroll
            for (int j = 0; j < 8; ++j) {
                vf0[j] = f2bf(vcol[(size_t)(kk + j) * D_]);
                vf1[j] = f2bf(vcol[(size_t)(kk + 32 + j) * D_]);
            }
            o0 = __builtin_amdgcn_mfma_f32_16x16x32_bf16(vf0, pf0, o0, 0, 0, 0);
            o1 = __builtin_amdgcn_mfma_f32_16x16x32_bf16(vf1, pf1, o1, 0, 0, 0);
        }
    }
    f32x4 o = (o0 + o2) + (o1 + o3);
    // D: col=l16 -> qrow, row=quad*4+r -> dcol n0+quad*4+r  => float4 ctx store
    float* crow = ctx + ((size_t)b * N_ + row0 + l16) * D_ + n0 + quad * 4;
    *(f32x4*)crow = o;
}

extern "C" void kernel_launch(void* const* d_in, const int* in_sizes, int n_in,
                              void* d_out, int out_size, void* d_ws, size_t ws_size,
                              hipStream_t stream) {
    const float* Q    = (const float*)d_in[0];
    const float* K    = (const float*)d_in[1];
    const float* V    = (const float*)d_in[2];
    const int*   mask = (const int*)d_in[3];

    float* out  = (float*)d_out;
    float* ctx  = out;                         // [B, N, D]
    float* attn = out + (size_t)B_ * N_ * D_;  // [B, N, N]

    dim3 grid(B_ * (N_ / TQ), 1, 1);           // 4096
    dim3 block(512, 1, 1);
    const size_t lds = (size_t)TQ * N_ * 2 + 2 * NW * TQ * sizeof(float);  // 66560 B

    const size_t nel = (size_t)B_ * N_ * D_;   // 8.39M elements
    const size_t ws_need = nel * 2 * 2;        // Kb + Vt bf16 = 32 MB

    if (ws_size >= ws_need) {
        ushort_t* Kb = (ushort_t*)d_ws;
        ushort_t* Vt = Kb + nel;
        conv_bf16_kernel<<<dim3((unsigned)(nel / 8 / 256)), dim3(256), 0, stream>>>(K, Kb);
        conv_vt_kernel<<<dim3(N_ / 32, D_ / 32, B_), dim3(256), 0, stream>>>(V, Vt);
        attn_fused_kernel<1><<<grid, block, lds, stream>>>(Q, K, Kb, V, Vt, mask, attn, ctx);
    } else {
        attn_fused_kernel<0><<<grid, block, lds, stream>>>(Q, K, (const ushort_t*)nullptr,
                                                           V, (const ushort_t*)nullptr,
                                                           mask, attn, ctx);
    }
}